// Round 12
// baseline (174.718 us; speedup 1.0000x reference)
//
#include <hip/hip_runtime.h>
#include <math.h>

#define BB 8
#define CH 128
#define HH 64
#define WWID 64
#define HIN 62
#define WIN 62
#define SPIN (HIN*WIN)      // 3844
#define HP 66
#define WP 66
#define GP2 70              // padded + 2-guard each side
#define GG 4
#define GCH 32
#define NPIX (BB*HH*WWID)   // 32768
#define ASTRIDE 136         // LDS A-tile row stride in halfs
#define XPHALFS ((size_t)BB*GP2*GP2*CH)   // 5,017,600 halfs

typedef _Float16 v8h __attribute__((ext_vector_type(8)));
typedef _Float16 v4h __attribute__((ext_vector_type(4)));
typedef float    v4f __attribute__((ext_vector_type(4)));
typedef float    f4a __attribute__((ext_vector_type(4), aligned(4)));

// ---- P0: pack weights into MFMA B-frag order + dwT + zero xpad -------------
__global__ __launch_bounds__(256) void p0_pack(const float* __restrict__ conv_w,
                                               const float* __restrict__ in_proj_w,
                                               const float* __restrict__ off_w,
                                               const float* __restrict__ mask_w,
                                               const float* __restrict__ out_proj_w,
                                               const float* __restrict__ dw_w,
                                               _Float16* __restrict__ wp,
                                               float* __restrict__ dwT,
                                               _Float16* __restrict__ xpad16) {
    int t = threadIdx.x;
    int blk = blockIdx.x;
    if (blk >= 32) {                                 // blocks 32..63: zero xpad
        size_t nvec = XPHALFS / 8;
        for (size_t i = (size_t)(blk - 32) * 256 + t; i < nvec; i += 32 * 256)
            *(v8h*)&xpad16[i * 8] = (v8h)(_Float16)0;
        return;
    }
    if (blk == 31) {                                 // dwT[tap][c] transpose
        if (t < 128) {
            #pragma unroll
            for (int tap = 0; tap < 9; tap++) dwT[tap * 128 + t] = dw_w[t * 9 + tap];
        }
        return;
    }
    int tid = blk * 256 + t;                         // 0..7935
    int mat, base;
    if (tid < 2048)      { mat = 0; base = 0; }
    else if (tid < 4096) { mat = 1; base = 2048; }
    else if (tid < 5888) { mat = 2; base = 4096; }
    else                 { mat = 3; base = 5888; }
    int fi = tid - base;
    int nt = fi >> 8, rem = fi & 255, kc = rem >> 6, lane = rem & 63;
    int n = nt * 16 + (lane & 15);
    int kbase = kc * 32 + ((lane >> 4) & 3) * 8;
    _Float16* dst = wp + (size_t)tid * 8;
    #pragma unroll
    for (int j = 0; j < 8; j++) {
        int k = kbase + j;
        float v;
        if (mat == 0)      v = conv_w[n * CH + k];
        else if (mat == 1) v = in_proj_w[k * CH + n];
        else if (mat == 2) v = (n < 72) ? off_w[k * 72 + n]
                               : (n < 108 ? mask_w[k * 36 + (n - 72)] : 0.f);
        else               v = out_proj_w[k * CH + n];
        dst[j] = (_Float16)v;
    }
}

// ---- MFMA core, 8-wave split (64-px tiles) ---------------------------------
__device__ inline void mfma_loop8(const _Float16* __restrict__ a16,
                                  const _Float16* __restrict__ wp,
                                  v4f acc[4], int t) {
    int lane = t & 63;
    int wv = t >> 6;
    int mt = wv >> 1, ntb = (wv & 1) * 4;
    const _Float16* abase = a16 + (mt * 16 + (lane & 15)) * ASTRIDE + ((lane >> 4) * 8);
    #pragma unroll
    for (int kc = 0; kc < 4; kc++) {
        v8h av = *(const v8h*)(abase + kc * 32);
        #pragma unroll
        for (int j = 0; j < 4; j++) {
            v8h bv = *(const v8h*)(wp + ((size_t)((ntb + j) * 4 + kc) * 64 + lane) * 8);
            acc[j] = __builtin_amdgcn_mfma_f32_16x16x32_f16(av, bv, acc[j], 0, 0, 0);
        }
    }
}

__device__ inline void acc_to_a16_8(_Float16* a16, v4f acc[4], int t) {
    int lane = t & 63, ncol = lane & 15;
    int wv = t >> 6;
    int m0 = (wv >> 1) * 16 + ((lane >> 4) * 4);
    int ntb = (wv & 1) * 4;
    #pragma unroll
    for (int j = 0; j < 4; j++)
        #pragma unroll
        for (int r = 0; r < 4; r++)
            a16[(m0 + r) * ASTRIDE + (ntb + j) * 16 + ncol] = (_Float16)acc[j][r];
}

// ---- gA: fused conv1x1(pad=1) + in_proj; emits y16 + xpad16 (70x70 guard) --
__global__ __launch_bounds__(512) void gA_conv_inproj(const float* __restrict__ x,
                                                      const _Float16* __restrict__ wp_conv,
                                                      const _Float16* __restrict__ wp_in,
                                                      const float* __restrict__ conv_b,
                                                      const float* __restrict__ in_b,
                                                      _Float16* __restrict__ y16,
                                                      _Float16* __restrict__ xpad16) {
    __shared__ _Float16 a16[64 * ASTRIDE];
    int pix0 = blockIdx.x * 64;                     // one row
    int t = threadIdx.x;
    int h = (pix0 >> 6) & 63, b = pix0 >> 12;
    bool hin = (h >= 1 && h <= 62);
    for (int q = t; q < 2048; q += 512) {
        int c = q >> 4, w4 = (q & 15) * 4;
        float4 v = make_float4(0.f, 0.f, 0.f, 0.f);
        if (hin) {
            const float* xr = x + ((size_t)(b * CH + c)) * SPIN + (h - 1) * WIN;
            if (w4 == 0)       { f4a e = *(const f4a*)&xr[0];      v = make_float4(0.f, e[0], e[1], e[2]); }
            else if (w4 == 60) { f4a e = *(const f4a*)&xr[58];     v = make_float4(e[1], e[2], e[3], 0.f); }
            else               { f4a e = *(const f4a*)&xr[w4 - 1]; v = make_float4(e[0], e[1], e[2], e[3]); }
        }
        a16[(w4 + 0) * ASTRIDE + c] = (_Float16)v.x;
        a16[(w4 + 1) * ASTRIDE + c] = (_Float16)v.y;
        a16[(w4 + 2) * ASTRIDE + c] = (_Float16)v.z;
        a16[(w4 + 3) * ASTRIDE + c] = (_Float16)v.w;
    }
    __syncthreads();
    int lane = t & 63, ncol = lane & 15;
    int ntb = ((t >> 6) & 1) * 4;
    v4f acc[4];
    #pragma unroll
    for (int j = 0; j < 4; j++) {
        float bv = conv_b[(ntb + j) * 16 + ncol];
        acc[j] = (v4f){bv, bv, bv, bv};
    }
    mfma_loop8(a16, wp_conv, acc, t);
    __syncthreads();
    acc_to_a16_8(a16, acc, t);                      // a16 = y tile
    __syncthreads();
    {
        _Float16* dst = y16 + (size_t)pix0 * CH;
        for (int q = t; q < 1024; q += 512)
            *(v8h*)&dst[q * 8] = *(const v8h*)&a16[(q >> 4) * ASTRIDE + (q & 15) * 8];
    }
    v4f acc2[4];
    #pragma unroll
    for (int j = 0; j < 4; j++) {
        float bv = in_b[(ntb + j) * 16 + ncol];
        acc2[j] = (v4f){bv, bv, bv, bv};
    }
    mfma_loop8(a16, wp_in, acc2, t);
    __syncthreads();
    acc_to_a16_8(a16, acc2, t);                     // a16 = x_proj tile
    __syncthreads();
    {
        _Float16* dst = xpad16 + (size_t)(((b * GP2) + h + 3) * GP2 + 3) * CH;
        for (int q = t; q < 1024; q += 512)
            *(v8h*)&dst[q * 8] = *(const v8h*)&a16[(q >> 4) * ASTRIDE + (q & 15) * 8];
    }
}

// ---- gF: fused dw3x3 + LN + GELU + off/mask MFMA + softmax + taps ----------
__global__ __launch_bounds__(512) void gF_dwln_offmask(const _Float16* __restrict__ y16,
                                                       const _Float16* __restrict__ wp_om,
                                                       const float* __restrict__ dwT,
                                                       const float* __restrict__ dw_b,
                                                       const float* __restrict__ ln_g,
                                                       const float* __restrict__ ln_b,
                                                       const float* __restrict__ off_b,
                                                       const float* __restrict__ mask_b,
                                                       float* __restrict__ tapmeta) {
    __shared__ char smem[49920];
    _Float16* ylds = (_Float16*)smem;               // v8h idx: (r*16+c8)*65 + w
    int t = threadIdx.x;
    int pix0 = blockIdx.x * 64;
    int h = (pix0 >> 6) & 63, b = pix0 >> 12;
    if (h == 0 || h == 63) {
        for (int i = t; i < 3120; i += 512) *(v8h*)&ylds[i * 8] = (v8h)(_Float16)0;
        __syncthreads();
    }
    for (int idx = t; idx < 3072; idx += 512) {
        int r = idx >> 10, w = (idx >> 4) & 63, c8 = idx & 15;
        int hh = h + r - 1;
        if (hh >= 0 && hh <= 63) {
            v8h v = *(const v8h*)&y16[(size_t)(((b * 64 + hh) * 64 + w) * CH) + c8 * 8];
            *(v8h*)&ylds[(size_t)((r * 16 + c8) * 65 + w) * 8] = v;
        }
    }
    __syncthreads();
    int px = t >> 3, q8 = t & 7;
    float acc[16];
    #pragma unroll
    for (int cb = 0; cb < 4; cb++) *(float4*)&acc[cb * 4] = *(const float4*)&dw_b[q8 * 16 + cb * 4];
    #pragma unroll
    for (int r = 0; r < 3; r++) {
        #pragma unroll
        for (int kx = 0; kx < 3; kx++) {
            int wq = px + kx - 1;
            bool valid = (wq >= 0 && wq <= 63);
            int wpc = min(max(wq, 0), 63);
            int tap = r * 3 + kx;
            if (valid) {
                #pragma unroll
                for (int cb = 0; cb < 2; cb++) {
                    v8h yv = *(const v8h*)&ylds[(size_t)((r * 16 + q8 * 2 + cb) * 65 + wpc) * 8];
                    float4 wa = *(const float4*)&dwT[tap * 128 + q8 * 16 + cb * 8];
                    float4 wb = *(const float4*)&dwT[tap * 128 + q8 * 16 + cb * 8 + 4];
                    acc[cb*8+0] += (float)yv[0] * wa.x; acc[cb*8+1] += (float)yv[1] * wa.y;
                    acc[cb*8+2] += (float)yv[2] * wa.z; acc[cb*8+3] += (float)yv[3] * wa.w;
                    acc[cb*8+4] += (float)yv[4] * wb.x; acc[cb*8+5] += (float)yv[5] * wb.y;
                    acc[cb*8+6] += (float)yv[6] * wb.z; acc[cb*8+7] += (float)yv[7] * wb.w;
                }
            }
        }
    }
    float s = 0.f, ss = 0.f;
    #pragma unroll
    for (int j = 0; j < 16; j++) { s += acc[j]; ss += acc[j] * acc[j]; }
    s  += __shfl_xor(s, 1);  s  += __shfl_xor(s, 2);  s  += __shfl_xor(s, 4);
    ss += __shfl_xor(ss, 1); ss += __shfl_xor(ss, 2); ss += __shfl_xor(ss, 4);
    float mu = s * (1.f / 128.f);
    float var = ss * (1.f / 128.f) - mu * mu;
    float rstd = rsqrtf(var + 1e-5f);
    v8h dreg[2];
    #pragma unroll
    for (int cb = 0; cb < 2; cb++) {
        float4 ga = *(const float4*)&ln_g[q8 * 16 + cb * 8];
        float4 gb = *(const float4*)&ln_g[q8 * 16 + cb * 8 + 4];
        float4 ba = *(const float4*)&ln_b[q8 * 16 + cb * 8];
        float4 bb = *(const float4*)&ln_b[q8 * 16 + cb * 8 + 4];
        float gv[8] = {ga.x, ga.y, ga.z, ga.w, gb.x, gb.y, gb.z, gb.w};
        float bv[8] = {ba.x, ba.y, ba.z, ba.w, bb.x, bb.y, bb.z, bb.w};
        #pragma unroll
        for (int j = 0; j < 8; j++) {
            float xln = (acc[cb * 8 + j] - mu) * rstd * gv[j] + bv[j];
            float gel = 0.5f * xln * (1.f + erff(xln * 0.70710678118654752f));
            dreg[cb][j] = (_Float16)gel;
        }
    }
    __syncthreads();
    _Float16* a16 = (_Float16*)smem;
    float* om = (float*)(smem + 17408);
    #pragma unroll
    for (int cb = 0; cb < 2; cb++)
        *(v8h*)&a16[px * ASTRIDE + q8 * 16 + cb * 8] = dreg[cb];
    __syncthreads();
    int lane = t & 63, ncol = lane & 15;
    int ntb = ((t >> 6) & 1) * 4;
    v4f macc[4];
    #pragma unroll
    for (int j = 0; j < 4; j++) {
        int n = (ntb + j) * 16 + ncol;
        float bv = (n < 72) ? off_b[n] : (n < 108 ? mask_b[n - 72] : 0.f);
        macc[j] = (v4f){bv, bv, bv, bv};
    }
    mfma_loop8(a16, wp_om, macc, t);
    int m0 = ((t >> 6) >> 1) * 16 + ((lane >> 4) * 4);
    #pragma unroll
    for (int j = 0; j < 4; j++) {
        if (ntb + j < 7) {
            #pragma unroll
            for (int r = 0; r < 4; r++)
                om[(m0 + r) * 112 + (ntb + j) * 16 + ncol] = macc[j][r];
        }
    }
    __syncthreads();
    {
        int job = t >> 1, half = t & 1;
        int pxs = job >> 2, gx = job & 3;
        const float* row = &om[pxs * 112];
        float lg[9];
        #pragma unroll
        for (int i = 0; i < 9; i++) lg[i] = row[72 + gx * 9 + i];
        float mx = lg[0];
        #pragma unroll
        for (int i = 1; i < 9; i++) mx = fmaxf(mx, lg[i]);
        float e[9], sum = 0.f;
        #pragma unroll
        for (int i = 0; i < 9; i++) { e[i] = expf(lg[i] - mx); sum += e[i]; }
        float inv = 1.f / sum;
        float* tm = tapmeta + ((size_t)(pix0 + pxs) * 36 + gx * 9) * 4;
        int pstart = half * 5;
        int pcount = half ? 4 : 5;
        #pragma unroll
        for (int pp = 0; pp < 5; pp++) {
            if (pp >= pcount) break;
            int p = pstart + pp;
            int gp = gx * 9 + p;
            float offx = row[gp * 2];
            float offy = row[gp * 2 + 1];
            float m = e[p] * inv;
            float ix = (float)(pxs + (p / 3)) + offx;
            float iy = (float)(h + (p % 3)) + offy;
            ix = fminf(fmaxf(ix, -2.f), (float)(WP + 1));
            iy = fminf(fmaxf(iy, -2.f), (float)(HP + 1));
            float x0f = floorf(ix), y0f = floorf(iy);
            float fx = ix - x0f, fy = iy - y0f;
            int x0 = (int)x0f, y0 = (int)y0f;
            int off = ((y0 + 2) * GP2 + (x0 + 2)) * CH;
            float4 rec;
            rec.x = __int_as_float(off);
            rec.y = fx; rec.z = fy; rec.w = m;
            *(float4*)&tm[p * 4] = rec;
        }
    }
}

// ---- gG: fused gather + out_proj, 16 px/block (2048 blocks, 128 thr) -------
// LDS: a16[16*ASTRIDE] (4352 B) | meta 576 f4 (9216 B, aliased by res 128x20 f32)
__global__ __launch_bounds__(128) void gG_gather_outproj(const _Float16* __restrict__ xpad16,
                                                         const float* __restrict__ tapmeta,
                                                         const _Float16* __restrict__ wp,
                                                         const float* __restrict__ bias,
                                                         float* __restrict__ out) {
    __shared__ char smem[14592];
    _Float16* a16 = (_Float16*)smem;                // 16 rows x ASTRIDE
    float* meta = (float*)(smem + 4352);            // 576 float4 (9216 B)
    float* res  = (float*)(smem + 4352);            // aliases meta; 128 x 20 f32
    int t = threadIdx.x;
    int pix0 = blockIdx.x * 16;
    int b = pix0 >> 12, h = (pix0 >> 6) & 63, wbase = pix0 & 63;
    // stage tap metadata: 16 px * 36 taps = 576 float4
    {
        const float4* src = (const float4*)(tapmeta + (size_t)pix0 * 36 * 4);
        for (int i = t; i < 576; i += 128) ((float4*)meta)[i] = src[i];
    }
    __syncthreads();
    // gather: px_l = t>>3 (0..15), slot s = t&7 -> 16 ch, group s>>1
    {
        int px_l = t >> 3, s = t & 7;
        int ch = s * 16, g = s >> 1;
        const _Float16* base = xpad16 + (size_t)b * GP2 * GP2 * CH + ch;
        const float* tmb = &meta[(size_t)(px_l * 36 + g * 9) * 4];
        float acc[16];
        #pragma unroll
        for (int j = 0; j < 16; j++) acc[j] = 0.f;
        #pragma unroll
        for (int p = 0; p < 9; p++) {
            float4 rec = *(const float4*)&tmb[p * 4];
            int off = __float_as_int(rec.x);
            float fx = rec.y, fy = rec.z, m = rec.w;
            float w11 = fx * fy;
            float w10 = fx - w11;
            float w01 = fy - w11;
            float w00 = 1.f - fx - fy + w11;
            w00 *= m; w10 *= m; w01 *= m; w11 *= m;
            v8h c0a = *(const v8h*)&base[off];
            v8h c0b = *(const v8h*)&base[off + 8];
            v8h c1a = *(const v8h*)&base[off + CH];
            v8h c1b = *(const v8h*)&base[off + CH + 8];
            v8h c2a = *(const v8h*)&base[off + GP2 * CH];
            v8h c2b = *(const v8h*)&base[off + GP2 * CH + 8];
            v8h c3a = *(const v8h*)&base[off + GP2 * CH + CH];
            v8h c3b = *(const v8h*)&base[off + GP2 * CH + CH + 8];
            #pragma unroll
            for (int j = 0; j < 8; j++) {
                acc[j]     += w00*(float)c0a[j] + w10*(float)c1a[j] + w01*(float)c2a[j] + w11*(float)c3a[j];
                acc[j + 8] += w00*(float)c0b[j] + w10*(float)c1b[j] + w01*(float)c2b[j] + w11*(float)c3b[j];
            }
        }
        v8h r0, r1;
        #pragma unroll
        for (int j = 0; j < 8; j++) { r0[j] = (_Float16)acc[j]; r1[j] = (_Float16)acc[j + 8]; }
        *(v8h*)&a16[px_l * ASTRIDE + ch]     = r0;
        *(v8h*)&a16[px_l * ASTRIDE + ch + 8] = r1;
    }
    __syncthreads();                                // meta dead after this point
    // out_proj MFMA: 2 waves, wave wv covers nt [wv*4, wv*4+4)
    int lane = t & 63, ncol = lane & 15;
    int ntb = (t >> 6) * 4;
    v4f macc[4];
    #pragma unroll
    for (int j = 0; j < 4; j++) {
        float bv = bias[(ntb + j) * 16 + ncol];
        macc[j] = (v4f){bv, bv, bv, bv};
    }
    {
        const _Float16* abase = a16 + (lane & 15) * ASTRIDE + ((lane >> 4) * 8);
        #pragma unroll
        for (int kc = 0; kc < 4; kc++) {
            v8h av = *(const v8h*)(abase + kc * 32);
            #pragma unroll
            for (int j = 0; j < 4; j++) {
                v8h bv = *(const v8h*)(wp + ((size_t)((ntb + j) * 4 + kc) * 64 + lane) * 8);
                macc[j] = __builtin_amdgcn_mfma_f32_16x16x32_f16(av, bv, macc[j], 0, 0, 0);
            }
        }
    }
    int m0 = (lane >> 4) * 4;
    #pragma unroll
    for (int j = 0; j < 4; j++)
        #pragma unroll
        for (int r = 0; r < 4; r++)
            res[((ntb + j) * 16 + ncol) * 20 + (m0 + r)] = macc[j][r];   // [c][w], stride 20
    __syncthreads();
    // NCHW store: 128 cc x 16 w; q -> cc = q>>2, w4 = (q&3)*4
    for (int q = t; q < 512; q += 128) {
        int cc = q >> 2, w4 = (q & 3) * 4;
        float4 o = *(const float4*)&res[cc * 20 + w4];
        *(float4*)&out[(size_t)((b * CH + cc) * HH + h) * WWID + wbase + w4] = o;
    }
}

extern "C" void kernel_launch(void* const* d_in, const int* in_sizes, int n_in,
                              void* d_out, int out_size, void* d_ws, size_t ws_size,
                              hipStream_t stream) {
    const float* x        = (const float*)d_in[0];
    const float* conv_w   = (const float*)d_in[1];
    const float* conv_b   = (const float*)d_in[2];
    const float* in_proj_w= (const float*)d_in[3];
    const float* in_proj_b= (const float*)d_in[4];
    const float* dw_w     = (const float*)d_in[5];
    const float* dw_b     = (const float*)d_in[6];
    const float* ln_g     = (const float*)d_in[7];
    const float* ln_b     = (const float*)d_in[8];
    const float* off_w    = (const float*)d_in[9];
    const float* off_b    = (const float*)d_in[10];
    const float* mask_w   = (const float*)d_in[11];
    const float* mask_b   = (const float*)d_in[12];
    const float* out_proj_w = (const float*)d_in[13];
    const float* out_proj_b = (const float*)d_in[14];
    float* out = (float*)d_out;

    float* ws = (float*)d_ws;
    // float-offsets: wp | dwT | y16 | xpad16(70x70 guard) | tapmeta
    const size_t O_WP   = 0;
    const size_t O_DWT  = 32768;
    const size_t O_Y16  = 34816;                    // 2,097,152 floats (halfs)
    const size_t O_XP16 = O_Y16 + 2097152;          // 2,508,800 floats
    const size_t O_TM   = O_XP16 + 2508800;         // 4,718,592 floats
    _Float16* wp     = (_Float16*)(ws + O_WP);
    float*    dwT    = ws + O_DWT;
    _Float16* y16    = (_Float16*)(ws + O_Y16);
    _Float16* xpad16 = (_Float16*)(ws + O_XP16);
    float*    tapmeta= ws + O_TM;

    _Float16* wp_conv = wp;
    _Float16* wp_in   = wp + (size_t)2048 * 8;
    _Float16* wp_om   = wp + (size_t)4096 * 8;
    _Float16* wp_out  = wp + (size_t)5888 * 8;

    p0_pack<<<64, 256, 0, stream>>>(conv_w, in_proj_w, off_w, mask_w, out_proj_w, dw_w, wp, dwT, xpad16);
    gA_conv_inproj<<<NPIX / 64, 512, 0, stream>>>(x, wp_conv, wp_in, conv_b, in_proj_b, y16, xpad16);
    gF_dwln_offmask<<<NPIX / 64, 512, 0, stream>>>(y16, wp_om, dwT, dw_b, ln_g, ln_b, off_b, mask_b, tapmeta);
    gG_gather_outproj<<<NPIX / 16, 128, 0, stream>>>(xpad16, tapmeta, wp_out, out_proj_b, out);
}

// Round 13
// 160.650 us; speedup vs baseline: 1.0876x; 1.0876x over previous
//
#include <hip/hip_runtime.h>
#include <math.h>

#define BB 8
#define CH 128
#define HH 64
#define WWID 64
#define HIN 62
#define WIN 62
#define SPIN (HIN*WIN)      // 3844
#define HP 66
#define WP 66
#define GP2 70              // padded + 2-guard each side
#define GG 4
#define GCH 32
#define NPIX (BB*HH*WWID)   // 32768
#define ASTRIDE 136         // LDS A-tile row stride in halfs
#define XPHALFS ((size_t)BB*GP2*GP2*CH)   // 5,017,600 halfs

typedef _Float16 v8h __attribute__((ext_vector_type(8)));
typedef _Float16 v4h __attribute__((ext_vector_type(4)));
typedef float    v4f __attribute__((ext_vector_type(4)));
typedef float    f4a __attribute__((ext_vector_type(4), aligned(4)));

// ---- P0: pack weights into MFMA B-frag order + dwT + zero xpad -------------
__global__ __launch_bounds__(256) void p0_pack(const float* __restrict__ conv_w,
                                               const float* __restrict__ in_proj_w,
                                               const float* __restrict__ off_w,
                                               const float* __restrict__ mask_w,
                                               const float* __restrict__ out_proj_w,
                                               const float* __restrict__ dw_w,
                                               _Float16* __restrict__ wp,
                                               float* __restrict__ dwT,
                                               _Float16* __restrict__ xpad16) {
    int t = threadIdx.x;
    int blk = blockIdx.x;
    if (blk >= 32) {                                 // blocks 32..63: zero xpad
        size_t nvec = XPHALFS / 8;
        for (size_t i = (size_t)(blk - 32) * 256 + t; i < nvec; i += 32 * 256)
            *(v8h*)&xpad16[i * 8] = (v8h)(_Float16)0;
        return;
    }
    if (blk == 31) {                                 // dwT[tap][c] transpose
        if (t < 128) {
            #pragma unroll
            for (int tap = 0; tap < 9; tap++) dwT[tap * 128 + t] = dw_w[t * 9 + tap];
        }
        return;
    }
    int tid = blk * 256 + t;                         // 0..7935
    int mat, base;
    if (tid < 2048)      { mat = 0; base = 0; }
    else if (tid < 4096) { mat = 1; base = 2048; }
    else if (tid < 5888) { mat = 2; base = 4096; }
    else                 { mat = 3; base = 5888; }
    int fi = tid - base;
    int nt = fi >> 8, rem = fi & 255, kc = rem >> 6, lane = rem & 63;
    int n = nt * 16 + (lane & 15);
    int kbase = kc * 32 + ((lane >> 4) & 3) * 8;
    _Float16* dst = wp + (size_t)tid * 8;
    #pragma unroll
    for (int j = 0; j < 8; j++) {
        int k = kbase + j;
        float v;
        if (mat == 0)      v = conv_w[n * CH + k];
        else if (mat == 1) v = in_proj_w[k * CH + n];
        else if (mat == 2) v = (n < 72) ? off_w[k * 72 + n]
                               : (n < 108 ? mask_w[k * 36 + (n - 72)] : 0.f);
        else               v = out_proj_w[k * CH + n];
        dst[j] = (_Float16)v;
    }
}

// ---- MFMA core, 8-wave split ----------------------------------------------
__device__ inline void mfma_loop8(const _Float16* __restrict__ a16,
                                  const _Float16* __restrict__ wp,
                                  v4f acc[4], int t) {
    int lane = t & 63;
    int wv = t >> 6;
    int mt = wv >> 1, ntb = (wv & 1) * 4;
    const _Float16* abase = a16 + (mt * 16 + (lane & 15)) * ASTRIDE + ((lane >> 4) * 8);
    #pragma unroll
    for (int kc = 0; kc < 4; kc++) {
        v8h av = *(const v8h*)(abase + kc * 32);
        #pragma unroll
        for (int j = 0; j < 4; j++) {
            v8h bv = *(const v8h*)(wp + ((size_t)((ntb + j) * 4 + kc) * 64 + lane) * 8);
            acc[j] = __builtin_amdgcn_mfma_f32_16x16x32_f16(av, bv, acc[j], 0, 0, 0);
        }
    }
}

__device__ inline void acc_to_a16_8(_Float16* a16, v4f acc[4], int t) {
    int lane = t & 63, ncol = lane & 15;
    int wv = t >> 6;
    int m0 = (wv >> 1) * 16 + ((lane >> 4) * 4);
    int ntb = (wv & 1) * 4;
    #pragma unroll
    for (int j = 0; j < 4; j++)
        #pragma unroll
        for (int r = 0; r < 4; r++)
            a16[(m0 + r) * ASTRIDE + (ntb + j) * 16 + ncol] = (_Float16)acc[j][r];
}

// ---- gA: fused conv1x1(pad=1) + in_proj; emits y16 + xpad16 (70x70 guard) --
__global__ __launch_bounds__(512) void gA_conv_inproj(const float* __restrict__ x,
                                                      const _Float16* __restrict__ wp_conv,
                                                      const _Float16* __restrict__ wp_in,
                                                      const float* __restrict__ conv_b,
                                                      const float* __restrict__ in_b,
                                                      _Float16* __restrict__ y16,
                                                      _Float16* __restrict__ xpad16) {
    __shared__ _Float16 a16[64 * ASTRIDE];
    int pix0 = blockIdx.x * 64;                     // one row
    int t = threadIdx.x;
    int h = (pix0 >> 6) & 63, b = pix0 >> 12;
    bool hin = (h >= 1 && h <= 62);
    for (int q = t; q < 2048; q += 512) {
        int c = q >> 4, w4 = (q & 15) * 4;
        float4 v = make_float4(0.f, 0.f, 0.f, 0.f);
        if (hin) {
            const float* xr = x + ((size_t)(b * CH + c)) * SPIN + (h - 1) * WIN;
            if (w4 == 0)       { f4a e = *(const f4a*)&xr[0];      v = make_float4(0.f, e[0], e[1], e[2]); }
            else if (w4 == 60) { f4a e = *(const f4a*)&xr[58];     v = make_float4(e[1], e[2], e[3], 0.f); }
            else               { f4a e = *(const f4a*)&xr[w4 - 1]; v = make_float4(e[0], e[1], e[2], e[3]); }
        }
        a16[(w4 + 0) * ASTRIDE + c] = (_Float16)v.x;
        a16[(w4 + 1) * ASTRIDE + c] = (_Float16)v.y;
        a16[(w4 + 2) * ASTRIDE + c] = (_Float16)v.z;
        a16[(w4 + 3) * ASTRIDE + c] = (_Float16)v.w;
    }
    __syncthreads();
    int lane = t & 63, ncol = lane & 15;
    int ntb = ((t >> 6) & 1) * 4;
    v4f acc[4];
    #pragma unroll
    for (int j = 0; j < 4; j++) {
        float bv = conv_b[(ntb + j) * 16 + ncol];
        acc[j] = (v4f){bv, bv, bv, bv};
    }
    mfma_loop8(a16, wp_conv, acc, t);
    __syncthreads();
    acc_to_a16_8(a16, acc, t);                      // a16 = y tile
    __syncthreads();
    {
        _Float16* dst = y16 + (size_t)pix0 * CH;
        for (int q = t; q < 1024; q += 512)
            *(v8h*)&dst[q * 8] = *(const v8h*)&a16[(q >> 4) * ASTRIDE + (q & 15) * 8];
    }
    v4f acc2[4];
    #pragma unroll
    for (int j = 0; j < 4; j++) {
        float bv = in_b[(ntb + j) * 16 + ncol];
        acc2[j] = (v4f){bv, bv, bv, bv};
    }
    mfma_loop8(a16, wp_in, acc2, t);
    __syncthreads();
    acc_to_a16_8(a16, acc2, t);                     // a16 = x_proj tile
    __syncthreads();
    {
        _Float16* dst = xpad16 + (size_t)(((b * GP2) + h + 3) * GP2 + 3) * CH;
        for (int q = t; q < 1024; q += 512)
            *(v8h*)&dst[q * 8] = *(const v8h*)&a16[(q >> 4) * ASTRIDE + (q & 15) * 8];
    }
}

// ---- gF: fused dw3x3 + LN + GELU + off/mask MFMA + softmax + taps ----------
__global__ __launch_bounds__(512) void gF_dwln_offmask(const _Float16* __restrict__ y16,
                                                       const _Float16* __restrict__ wp_om,
                                                       const float* __restrict__ dwT,
                                                       const float* __restrict__ dw_b,
                                                       const float* __restrict__ ln_g,
                                                       const float* __restrict__ ln_b,
                                                       const float* __restrict__ off_b,
                                                       const float* __restrict__ mask_b,
                                                       float* __restrict__ tapmeta) {
    __shared__ char smem[49920];
    _Float16* ylds = (_Float16*)smem;               // v8h idx: (r*16+c8)*65 + w
    int t = threadIdx.x;
    int pix0 = blockIdx.x * 64;
    int h = (pix0 >> 6) & 63, b = pix0 >> 12;
    if (h == 0 || h == 63) {
        for (int i = t; i < 3120; i += 512) *(v8h*)&ylds[i * 8] = (v8h)(_Float16)0;
        __syncthreads();
    }
    for (int idx = t; idx < 3072; idx += 512) {
        int r = idx >> 10, w = (idx >> 4) & 63, c8 = idx & 15;
        int hh = h + r - 1;
        if (hh >= 0 && hh <= 63) {
            v8h v = *(const v8h*)&y16[(size_t)(((b * 64 + hh) * 64 + w) * CH) + c8 * 8];
            *(v8h*)&ylds[(size_t)((r * 16 + c8) * 65 + w) * 8] = v;
        }
    }
    __syncthreads();
    int px = t >> 3, q8 = t & 7;
    float acc[16];
    #pragma unroll
    for (int cb = 0; cb < 4; cb++) *(float4*)&acc[cb * 4] = *(const float4*)&dw_b[q8 * 16 + cb * 4];
    #pragma unroll
    for (int r = 0; r < 3; r++) {
        #pragma unroll
        for (int kx = 0; kx < 3; kx++) {
            int wq = px + kx - 1;
            bool valid = (wq >= 0 && wq <= 63);
            int wpc = min(max(wq, 0), 63);
            int tap = r * 3 + kx;
            if (valid) {
                #pragma unroll
                for (int cb = 0; cb < 2; cb++) {
                    v8h yv = *(const v8h*)&ylds[(size_t)((r * 16 + q8 * 2 + cb) * 65 + wpc) * 8];
                    float4 wa = *(const float4*)&dwT[tap * 128 + q8 * 16 + cb * 8];
                    float4 wb = *(const float4*)&dwT[tap * 128 + q8 * 16 + cb * 8 + 4];
                    acc[cb*8+0] += (float)yv[0] * wa.x; acc[cb*8+1] += (float)yv[1] * wa.y;
                    acc[cb*8+2] += (float)yv[2] * wa.z; acc[cb*8+3] += (float)yv[3] * wa.w;
                    acc[cb*8+4] += (float)yv[4] * wb.x; acc[cb*8+5] += (float)yv[5] * wb.y;
                    acc[cb*8+6] += (float)yv[6] * wb.z; acc[cb*8+7] += (float)yv[7] * wb.w;
                }
            }
        }
    }
    float s = 0.f, ss = 0.f;
    #pragma unroll
    for (int j = 0; j < 16; j++) { s += acc[j]; ss += acc[j] * acc[j]; }
    s  += __shfl_xor(s, 1);  s  += __shfl_xor(s, 2);  s  += __shfl_xor(s, 4);
    ss += __shfl_xor(ss, 1); ss += __shfl_xor(ss, 2); ss += __shfl_xor(ss, 4);
    float mu = s * (1.f / 128.f);
    float var = ss * (1.f / 128.f) - mu * mu;
    float rstd = rsqrtf(var + 1e-5f);
    v8h dreg[2];
    #pragma unroll
    for (int cb = 0; cb < 2; cb++) {
        float4 ga = *(const float4*)&ln_g[q8 * 16 + cb * 8];
        float4 gb = *(const float4*)&ln_g[q8 * 16 + cb * 8 + 4];
        float4 ba = *(const float4*)&ln_b[q8 * 16 + cb * 8];
        float4 bb = *(const float4*)&ln_b[q8 * 16 + cb * 8 + 4];
        float gv[8] = {ga.x, ga.y, ga.z, ga.w, gb.x, gb.y, gb.z, gb.w};
        float bv[8] = {ba.x, ba.y, ba.z, ba.w, bb.x, bb.y, bb.z, bb.w};
        #pragma unroll
        for (int j = 0; j < 8; j++) {
            float xln = (acc[cb * 8 + j] - mu) * rstd * gv[j] + bv[j];
            float gel = 0.5f * xln * (1.f + erff(xln * 0.70710678118654752f));
            dreg[cb][j] = (_Float16)gel;
        }
    }
    __syncthreads();
    _Float16* a16 = (_Float16*)smem;
    float* om = (float*)(smem + 17408);
    #pragma unroll
    for (int cb = 0; cb < 2; cb++)
        *(v8h*)&a16[px * ASTRIDE + q8 * 16 + cb * 8] = dreg[cb];
    __syncthreads();
    int lane = t & 63, ncol = lane & 15;
    int ntb = ((t >> 6) & 1) * 4;
    v4f macc[4];
    #pragma unroll
    for (int j = 0; j < 4; j++) {
        int n = (ntb + j) * 16 + ncol;
        float bv = (n < 72) ? off_b[n] : (n < 108 ? mask_b[n - 72] : 0.f);
        macc[j] = (v4f){bv, bv, bv, bv};
    }
    mfma_loop8(a16, wp_om, macc, t);
    int m0 = ((t >> 6) >> 1) * 16 + ((lane >> 4) * 4);
    #pragma unroll
    for (int j = 0; j < 4; j++) {
        if (ntb + j < 7) {
            #pragma unroll
            for (int r = 0; r < 4; r++)
                om[(m0 + r) * 112 + (ntb + j) * 16 + ncol] = macc[j][r];
        }
    }
    __syncthreads();
    {
        int job = t >> 1, half = t & 1;
        int pxs = job >> 2, gx = job & 3;
        const float* row = &om[pxs * 112];
        float lg[9];
        #pragma unroll
        for (int i = 0; i < 9; i++) lg[i] = row[72 + gx * 9 + i];
        float mx = lg[0];
        #pragma unroll
        for (int i = 1; i < 9; i++) mx = fmaxf(mx, lg[i]);
        float e[9], sum = 0.f;
        #pragma unroll
        for (int i = 0; i < 9; i++) { e[i] = expf(lg[i] - mx); sum += e[i]; }
        float inv = 1.f / sum;
        float* tm = tapmeta + ((size_t)(pix0 + pxs) * 36 + gx * 9) * 4;
        int pstart = half * 5;
        int pcount = half ? 4 : 5;
        #pragma unroll
        for (int pp = 0; pp < 5; pp++) {
            if (pp >= pcount) break;
            int p = pstart + pp;
            int gp = gx * 9 + p;
            float offx = row[gp * 2];
            float offy = row[gp * 2 + 1];
            float m = e[p] * inv;
            float ix = (float)(pxs + (p / 3)) + offx;
            float iy = (float)(h + (p % 3)) + offy;
            ix = fminf(fmaxf(ix, -2.f), (float)(WP + 1));
            iy = fminf(fmaxf(iy, -2.f), (float)(HP + 1));
            float x0f = floorf(ix), y0f = floorf(iy);
            float fx = ix - x0f, fy = iy - y0f;
            int x0 = (int)x0f, y0 = (int)y0f;
            int off = ((y0 + 2) * GP2 + (x0 + 2)) * CH;
            float4 rec;
            rec.x = __int_as_float(off);
            rec.y = fx; rec.z = fy; rec.w = m;
            *(float4*)&tm[p * 4] = rec;
        }
    }
}

// ---- kD: gather sampling, 16 px/block, 8 ch/thread (v8h) -> core16 ---------
__global__ __launch_bounds__(256) void kD_gather(const _Float16* __restrict__ xpad16,
                                                 const float* __restrict__ tapmeta,
                                                 _Float16* __restrict__ core16) {
    __shared__ float meta[16 * 36 * 4];             // 576 float4 = 9216 B
    int t = threadIdx.x;
    int pix0 = blockIdx.x * 16;
    const float4* src = (const float4*)(tapmeta + (size_t)pix0 * 36 * 4);
    for (int i = t; i < 576; i += 256) ((float4*)meta)[i] = src[i];
    __syncthreads();
    int px_l = t >> 4, s = t & 15;                  // px 0..15, slot 0..15
    int ch = s * 8, g = s >> 2;                     // 8 ch/thread, group = s/4
    int pix = pix0 + px_l;
    int b = pix >> 12;
    const _Float16* base = xpad16 + (size_t)b * GP2 * GP2 * CH + ch;
    const float* tmb = &meta[(size_t)(px_l * 36 + g * 9) * 4];
    float acc[8];
    #pragma unroll
    for (int j = 0; j < 8; j++) acc[j] = 0.f;
    #pragma unroll
    for (int p = 0; p < 9; p++) {
        float4 rec = *(const float4*)&tmb[p * 4];
        int off = __float_as_int(rec.x);
        float fx = rec.y, fy = rec.z, m = rec.w;
        float w11 = fx * fy;
        float w10 = fx - w11;
        float w01 = fy - w11;
        float w00 = 1.f - fx - fy + w11;
        w00 *= m; w10 *= m; w01 *= m; w11 *= m;
        v8h h0 = *(const v8h*)&base[off];
        v8h h1 = *(const v8h*)&base[off + CH];
        v8h h2 = *(const v8h*)&base[off + GP2 * CH];
        v8h h3 = *(const v8h*)&base[off + GP2 * CH + CH];
        #pragma unroll
        for (int j = 0; j < 8; j++)
            acc[j] += w00*(float)h0[j] + w10*(float)h1[j] + w01*(float)h2[j] + w11*(float)h3[j];
    }
    v8h res;
    #pragma unroll
    for (int j = 0; j < 8; j++) res[j] = (_Float16)acc[j];
    *(v8h*)&core16[(size_t)pix * CH + ch] = res;
}

// ---- g4: out_proj via MFMA + NHWC->NCHW store ------------------------------
__global__ __launch_bounds__(512) void g4_outproj(const _Float16* __restrict__ core16,
                                                  const _Float16* __restrict__ wp,
                                                  const float* __restrict__ bias,
                                                  float* __restrict__ out) {
    __shared__ _Float16 a16[64 * ASTRIDE];
    __shared__ float res[128 * 68];                 // [c][w], stride 68
    int pix0 = blockIdx.x * 64;
    int t = threadIdx.x;
    const _Float16* src = core16 + (size_t)pix0 * CH;
    for (int q = t; q < 1024; q += 512)
        *(v8h*)&a16[(q >> 4) * ASTRIDE + (q & 15) * 8] = *(const v8h*)&src[q * 8];
    __syncthreads();
    int lane = t & 63, ncol = lane & 15;
    int ntb = ((t >> 6) & 1) * 4;
    v4f acc[4];
    #pragma unroll
    for (int j = 0; j < 4; j++) {
        float bv = bias[(ntb + j) * 16 + ncol];
        acc[j] = (v4f){bv, bv, bv, bv};
    }
    mfma_loop8(a16, wp, acc, t);
    int m0 = ((t >> 6) >> 1) * 16 + ((lane >> 4) * 4);
    #pragma unroll
    for (int j = 0; j < 4; j++)
        #pragma unroll
        for (int r = 0; r < 4; r++)
            res[((ntb + j) * 16 + ncol) * 68 + (m0 + r)] = acc[j][r];  // [c][w]
    __syncthreads();
    int b = pix0 >> 12, h = (pix0 >> 6) & 63;
    for (int q = t; q < 2048; q += 512) {
        int cc = q >> 4, w4 = (q & 15) * 4;
        float4 o = *(const float4*)&res[cc * 68 + w4];   // vector LDS read
        *(float4*)&out[(size_t)((b * CH + cc) * HH + h) * WWID + w4] = o;
    }
}

extern "C" void kernel_launch(void* const* d_in, const int* in_sizes, int n_in,
                              void* d_out, int out_size, void* d_ws, size_t ws_size,
                              hipStream_t stream) {
    const float* x        = (const float*)d_in[0];
    const float* conv_w   = (const float*)d_in[1];
    const float* conv_b   = (const float*)d_in[2];
    const float* in_proj_w= (const float*)d_in[3];
    const float* in_proj_b= (const float*)d_in[4];
    const float* dw_w     = (const float*)d_in[5];
    const float* dw_b     = (const float*)d_in[6];
    const float* ln_g     = (const float*)d_in[7];
    const float* ln_b     = (const float*)d_in[8];
    const float* off_w    = (const float*)d_in[9];
    const float* off_b    = (const float*)d_in[10];
    const float* mask_w   = (const float*)d_in[11];
    const float* mask_b   = (const float*)d_in[12];
    const float* out_proj_w = (const float*)d_in[13];
    const float* out_proj_b = (const float*)d_in[14];
    float* out = (float*)d_out;

    float* ws = (float*)d_ws;
    // float-offsets: wp | dwT | y16 | xpad16(70x70 guard) | core16 | tapmeta
    const size_t O_WP   = 0;
    const size_t O_DWT  = 32768;
    const size_t O_Y16  = 34816;                    // 2,097,152 floats (halfs)
    const size_t O_XP16 = O_Y16 + 2097152;          // 2,508,800 floats
    const size_t O_C16  = O_XP16 + 2508800;         // 2,097,152 floats
    const size_t O_TM   = O_C16 + 2097152;          // 4,718,592 floats
    _Float16* wp     = (_Float16*)(ws + O_WP);
    float*    dwT    = ws + O_DWT;
    _Float16* y16    = (_Float16*)(ws + O_Y16);
    _Float16* xpad16 = (_Float16*)(ws + O_XP16);
    _Float16* core16 = (_Float16*)(ws + O_C16);
    float*    tapmeta= ws + O_TM;

    _Float16* wp_conv = wp;
    _Float16* wp_in   = wp + (size_t)2048 * 8;
    _Float16* wp_om   = wp + (size_t)4096 * 8;
    _Float16* wp_out  = wp + (size_t)5888 * 8;

    p0_pack<<<64, 256, 0, stream>>>(conv_w, in_proj_w, off_w, mask_w, out_proj_w, dw_w, wp, dwT, xpad16);
    gA_conv_inproj<<<NPIX / 64, 512, 0, stream>>>(x, wp_conv, wp_in, conv_b, in_proj_b, y16, xpad16);
    gF_dwln_offmask<<<NPIX / 64, 512, 0, stream>>>(y16, wp_om, dwT, dw_b, ln_g, ln_b, off_b, mask_b, tapmeta);
    kD_gather<<<NPIX / 16, 256, 0, stream>>>(xpad16, tapmeta, core16);
    g4_outproj<<<NPIX / 64, 512, 0, stream>>>(core16, wp_out, out_proj_b, out);
}

// Round 14
// 158.765 us; speedup vs baseline: 1.1005x; 1.0119x over previous
//
#include <hip/hip_runtime.h>
#include <math.h>

#define BB 8
#define CH 128
#define HH 64
#define WWID 64
#define HIN 62
#define WIN 62
#define SPIN (HIN*WIN)      // 3844
#define HP 66
#define WP 66
#define GP2 70              // padded + 2-guard each side
#define GG 4
#define GCH 32
#define NPIX (BB*HH*WWID)   // 32768
#define ASTRIDE 136         // LDS A-tile row stride in halfs
#define XPHALFS ((size_t)BB*GP2*GP2*CH)   // 5,017,600 halfs

typedef _Float16 v8h __attribute__((ext_vector_type(8)));
typedef _Float16 v4h __attribute__((ext_vector_type(4)));
typedef float    v4f __attribute__((ext_vector_type(4)));
typedef float    f4a __attribute__((ext_vector_type(4), aligned(4)));

// XCD-aware swizzle: XCD k (round-robin bid%8) gets a contiguous slab of
// blocks -> per-XCD L2 sees one batch image only (perf heuristic, G16-safe).
__device__ inline int xcd_swizzle(int bid, int nblk8) {
    return (bid & 7) * nblk8 + (bid >> 3);
}

// ---- P0: pack weights into MFMA B-frag order + dwT + zero xpad -------------
__global__ __launch_bounds__(256) void p0_pack(const float* __restrict__ conv_w,
                                               const float* __restrict__ in_proj_w,
                                               const float* __restrict__ off_w,
                                               const float* __restrict__ mask_w,
                                               const float* __restrict__ out_proj_w,
                                               const float* __restrict__ dw_w,
                                               _Float16* __restrict__ wp,
                                               float* __restrict__ dwT,
                                               _Float16* __restrict__ xpad16) {
    int t = threadIdx.x;
    int blk = blockIdx.x;
    if (blk >= 32) {                                 // blocks 32..63: zero xpad
        size_t nvec = XPHALFS / 8;
        for (size_t i = (size_t)(blk - 32) * 256 + t; i < nvec; i += 32 * 256)
            *(v8h*)&xpad16[i * 8] = (v8h)(_Float16)0;
        return;
    }
    if (blk == 31) {                                 // dwT[tap][c] transpose
        if (t < 128) {
            #pragma unroll
            for (int tap = 0; tap < 9; tap++) dwT[tap * 128 + t] = dw_w[t * 9 + tap];
        }
        return;
    }
    int tid = blk * 256 + t;                         // 0..7935
    int mat, base;
    if (tid < 2048)      { mat = 0; base = 0; }
    else if (tid < 4096) { mat = 1; base = 2048; }
    else if (tid < 5888) { mat = 2; base = 4096; }
    else                 { mat = 3; base = 5888; }
    int fi = tid - base;
    int nt = fi >> 8, rem = fi & 255, kc = rem >> 6, lane = rem & 63;
    int n = nt * 16 + (lane & 15);
    int kbase = kc * 32 + ((lane >> 4) & 3) * 8;
    _Float16* dst = wp + (size_t)tid * 8;
    #pragma unroll
    for (int j = 0; j < 8; j++) {
        int k = kbase + j;
        float v;
        if (mat == 0)      v = conv_w[n * CH + k];
        else if (mat == 1) v = in_proj_w[k * CH + n];
        else if (mat == 2) v = (n < 72) ? off_w[k * 72 + n]
                               : (n < 108 ? mask_w[k * 36 + (n - 72)] : 0.f);
        else               v = out_proj_w[k * CH + n];
        dst[j] = (_Float16)v;
    }
}

// ---- MFMA core (works for 4- or 8-wave blocks): wave wv -> mt=wv>>1, ntb=(wv&1)*4
__device__ inline void mfma_loop8(const _Float16* __restrict__ a16,
                                  const _Float16* __restrict__ wp,
                                  v4f acc[4], int t) {
    int lane = t & 63;
    int wv = t >> 6;
    int mt = wv >> 1, ntb = (wv & 1) * 4;
    const _Float16* abase = a16 + (mt * 16 + (lane & 15)) * ASTRIDE + ((lane >> 4) * 8);
    #pragma unroll
    for (int kc = 0; kc < 4; kc++) {
        v8h av = *(const v8h*)(abase + kc * 32);
        #pragma unroll
        for (int j = 0; j < 4; j++) {
            v8h bv = *(const v8h*)(wp + ((size_t)((ntb + j) * 4 + kc) * 64 + lane) * 8);
            acc[j] = __builtin_amdgcn_mfma_f32_16x16x32_f16(av, bv, acc[j], 0, 0, 0);
        }
    }
}

__device__ inline void acc_to_a16_8(_Float16* a16, v4f acc[4], int t) {
    int lane = t & 63, ncol = lane & 15;
    int wv = t >> 6;
    int m0 = (wv >> 1) * 16 + ((lane >> 4) * 4);
    int ntb = (wv & 1) * 4;
    #pragma unroll
    for (int j = 0; j < 4; j++)
        #pragma unroll
        for (int r = 0; r < 4; r++)
            a16[(m0 + r) * ASTRIDE + (ntb + j) * 16 + ncol] = (_Float16)acc[j][r];
}

// ---- gA: fused conv1x1(pad=1) + in_proj; 32 px/block, 256 thr --------------
__global__ __launch_bounds__(256) void gA_conv_inproj(const float* __restrict__ x,
                                                      const _Float16* __restrict__ wp_conv,
                                                      const _Float16* __restrict__ wp_in,
                                                      const float* __restrict__ conv_b,
                                                      const float* __restrict__ in_b,
                                                      _Float16* __restrict__ y16,
                                                      _Float16* __restrict__ xpad16) {
    __shared__ _Float16 a16[32 * ASTRIDE];          // 8.7 KB
    int eff = xcd_swizzle(blockIdx.x, 128);         // 1024 blocks -> batch-per-XCD
    int pix0 = eff * 32;                            // half a row
    int t = threadIdx.x;
    int h = (pix0 >> 6) & 63, b = pix0 >> 12, wb = pix0 & 63;  // wb = 0 or 32
    bool hin = (h >= 1 && h <= 62);
    for (int q = t; q < 1024; q += 256) {
        int c = q >> 3, w4l = (q & 7) * 4;
        int w4 = wb + w4l;                          // global w of first elem
        float4 v = make_float4(0.f, 0.f, 0.f, 0.f);
        if (hin) {
            const float* xr = x + ((size_t)(b * CH + c)) * SPIN + (h - 1) * WIN;
            if (w4 == 0)       { f4a e = *(const f4a*)&xr[0];      v = make_float4(0.f, e[0], e[1], e[2]); }
            else if (w4 == 60) { f4a e = *(const f4a*)&xr[58];     v = make_float4(e[1], e[2], e[3], 0.f); }
            else               { f4a e = *(const f4a*)&xr[w4 - 1]; v = make_float4(e[0], e[1], e[2], e[3]); }
        }
        a16[(w4l + 0) * ASTRIDE + c] = (_Float16)v.x;
        a16[(w4l + 1) * ASTRIDE + c] = (_Float16)v.y;
        a16[(w4l + 2) * ASTRIDE + c] = (_Float16)v.z;
        a16[(w4l + 3) * ASTRIDE + c] = (_Float16)v.w;
    }
    __syncthreads();
    int lane = t & 63, ncol = lane & 15;
    int ntb = ((t >> 6) & 1) * 4;
    v4f acc[4];
    #pragma unroll
    for (int j = 0; j < 4; j++) {
        float bv = conv_b[(ntb + j) * 16 + ncol];
        acc[j] = (v4f){bv, bv, bv, bv};
    }
    mfma_loop8(a16, wp_conv, acc, t);
    __syncthreads();
    acc_to_a16_8(a16, acc, t);                      // a16 = y tile
    __syncthreads();
    {
        _Float16* dst = y16 + (size_t)pix0 * CH;
        for (int q = t; q < 512; q += 256)
            *(v8h*)&dst[q * 8] = *(const v8h*)&a16[(q >> 4) * ASTRIDE + (q & 15) * 8];
    }
    v4f acc2[4];
    #pragma unroll
    for (int j = 0; j < 4; j++) {
        float bv = in_b[(ntb + j) * 16 + ncol];
        acc2[j] = (v4f){bv, bv, bv, bv};
    }
    mfma_loop8(a16, wp_in, acc2, t);
    __syncthreads();
    acc_to_a16_8(a16, acc2, t);                     // a16 = x_proj tile
    __syncthreads();
    {
        _Float16* dst = xpad16 + (size_t)(((b * GP2) + h + 3) * GP2 + 3 + wb) * CH;
        for (int q = t; q < 512; q += 256)
            *(v8h*)&dst[q * 8] = *(const v8h*)&a16[(q >> 4) * ASTRIDE + (q & 15) * 8];
    }
}

// ---- gF: fused dw3x3 + LN + GELU + off/mask MFMA + softmax + taps ----------
__global__ __launch_bounds__(512) void gF_dwln_offmask(const _Float16* __restrict__ y16,
                                                       const _Float16* __restrict__ wp_om,
                                                       const float* __restrict__ dwT,
                                                       const float* __restrict__ dw_b,
                                                       const float* __restrict__ ln_g,
                                                       const float* __restrict__ ln_b,
                                                       const float* __restrict__ off_b,
                                                       const float* __restrict__ mask_b,
                                                       float* __restrict__ tapmeta) {
    __shared__ char smem[49920];
    _Float16* ylds = (_Float16*)smem;               // v8h idx: (r*16+c8)*65 + w
    int t = threadIdx.x;
    int eff = xcd_swizzle(blockIdx.x, 64);          // 512 blocks -> batch-per-XCD
    int pix0 = eff * 64;
    int h = (pix0 >> 6) & 63, b = pix0 >> 12;
    if (h == 0 || h == 63) {
        for (int i = t; i < 3120; i += 512) *(v8h*)&ylds[i * 8] = (v8h)(_Float16)0;
        __syncthreads();
    }
    for (int idx = t; idx < 3072; idx += 512) {
        int r = idx >> 10, w = (idx >> 4) & 63, c8 = idx & 15;
        int hh = h + r - 1;
        if (hh >= 0 && hh <= 63) {
            v8h v = *(const v8h*)&y16[(size_t)(((b * 64 + hh) * 64 + w) * CH) + c8 * 8];
            *(v8h*)&ylds[(size_t)((r * 16 + c8) * 65 + w) * 8] = v;
        }
    }
    __syncthreads();
    int px = t >> 3, q8 = t & 7;
    float acc[16];
    #pragma unroll
    for (int cb = 0; cb < 4; cb++) *(float4*)&acc[cb * 4] = *(const float4*)&dw_b[q8 * 16 + cb * 4];
    #pragma unroll
    for (int r = 0; r < 3; r++) {
        #pragma unroll
        for (int kx = 0; kx < 3; kx++) {
            int wq = px + kx - 1;
            bool valid = (wq >= 0 && wq <= 63);
            int wpc = min(max(wq, 0), 63);
            int tap = r * 3 + kx;
            if (valid) {
                #pragma unroll
                for (int cb = 0; cb < 2; cb++) {
                    v8h yv = *(const v8h*)&ylds[(size_t)((r * 16 + q8 * 2 + cb) * 65 + wpc) * 8];
                    float4 wa = *(const float4*)&dwT[tap * 128 + q8 * 16 + cb * 8];
                    float4 wb = *(const float4*)&dwT[tap * 128 + q8 * 16 + cb * 8 + 4];
                    acc[cb*8+0] += (float)yv[0] * wa.x; acc[cb*8+1] += (float)yv[1] * wa.y;
                    acc[cb*8+2] += (float)yv[2] * wa.z; acc[cb*8+3] += (float)yv[3] * wa.w;
                    acc[cb*8+4] += (float)yv[4] * wb.x; acc[cb*8+5] += (float)yv[5] * wb.y;
                    acc[cb*8+6] += (float)yv[6] * wb.z; acc[cb*8+7] += (float)yv[7] * wb.w;
                }
            }
        }
    }
    float s = 0.f, ss = 0.f;
    #pragma unroll
    for (int j = 0; j < 16; j++) { s += acc[j]; ss += acc[j] * acc[j]; }
    s  += __shfl_xor(s, 1);  s  += __shfl_xor(s, 2);  s  += __shfl_xor(s, 4);
    ss += __shfl_xor(ss, 1); ss += __shfl_xor(ss, 2); ss += __shfl_xor(ss, 4);
    float mu = s * (1.f / 128.f);
    float var = ss * (1.f / 128.f) - mu * mu;
    float rstd = rsqrtf(var + 1e-5f);
    v8h dreg[2];
    #pragma unroll
    for (int cb = 0; cb < 2; cb++) {
        float4 ga = *(const float4*)&ln_g[q8 * 16 + cb * 8];
        float4 gb = *(const float4*)&ln_g[q8 * 16 + cb * 8 + 4];
        float4 ba = *(const float4*)&ln_b[q8 * 16 + cb * 8];
        float4 bb = *(const float4*)&ln_b[q8 * 16 + cb * 8 + 4];
        float gv[8] = {ga.x, ga.y, ga.z, ga.w, gb.x, gb.y, gb.z, gb.w};
        float bv[8] = {ba.x, ba.y, ba.z, ba.w, bb.x, bb.y, bb.z, bb.w};
        #pragma unroll
        for (int j = 0; j < 8; j++) {
            float xln = (acc[cb * 8 + j] - mu) * rstd * gv[j] + bv[j];
            float gel = 0.5f * xln * (1.f + erff(xln * 0.70710678118654752f));
            dreg[cb][j] = (_Float16)gel;
        }
    }
    __syncthreads();
    _Float16* a16 = (_Float16*)smem;
    float* om = (float*)(smem + 17408);
    #pragma unroll
    for (int cb = 0; cb < 2; cb++)
        *(v8h*)&a16[px * ASTRIDE + q8 * 16 + cb * 8] = dreg[cb];
    __syncthreads();
    int lane = t & 63, ncol = lane & 15;
    int ntb = ((t >> 6) & 1) * 4;
    v4f macc[4];
    #pragma unroll
    for (int j = 0; j < 4; j++) {
        int n = (ntb + j) * 16 + ncol;
        float bv = (n < 72) ? off_b[n] : (n < 108 ? mask_b[n - 72] : 0.f);
        macc[j] = (v4f){bv, bv, bv, bv};
    }
    mfma_loop8(a16, wp_om, macc, t);
    int m0 = ((t >> 6) >> 1) * 16 + ((lane >> 4) * 4);
    #pragma unroll
    for (int j = 0; j < 4; j++) {
        if (ntb + j < 7) {
            #pragma unroll
            for (int r = 0; r < 4; r++)
                om[(m0 + r) * 112 + (ntb + j) * 16 + ncol] = macc[j][r];
        }
    }
    __syncthreads();
    {
        int job = t >> 1, half = t & 1;
        int pxs = job >> 2, gx = job & 3;
        const float* row = &om[pxs * 112];
        float lg[9];
        #pragma unroll
        for (int i = 0; i < 9; i++) lg[i] = row[72 + gx * 9 + i];
        float mx = lg[0];
        #pragma unroll
        for (int i = 1; i < 9; i++) mx = fmaxf(mx, lg[i]);
        float e[9], sum = 0.f;
        #pragma unroll
        for (int i = 0; i < 9; i++) { e[i] = expf(lg[i] - mx); sum += e[i]; }
        float inv = 1.f / sum;
        float* tm = tapmeta + ((size_t)(pix0 + pxs) * 36 + gx * 9) * 4;
        int pstart = half * 5;
        int pcount = half ? 4 : 5;
        #pragma unroll
        for (int pp = 0; pp < 5; pp++) {
            if (pp >= pcount) break;
            int p = pstart + pp;
            int gp = gx * 9 + p;
            float offx = row[gp * 2];
            float offy = row[gp * 2 + 1];
            float m = e[p] * inv;
            float ix = (float)(pxs + (p / 3)) + offx;
            float iy = (float)(h + (p % 3)) + offy;
            ix = fminf(fmaxf(ix, -2.f), (float)(WP + 1));
            iy = fminf(fmaxf(iy, -2.f), (float)(HP + 1));
            float x0f = floorf(ix), y0f = floorf(iy);
            float fx = ix - x0f, fy = iy - y0f;
            int x0 = (int)x0f, y0 = (int)y0f;
            int off = ((y0 + 2) * GP2 + (x0 + 2)) * CH;
            float4 rec;
            rec.x = __int_as_float(off);
            rec.y = fx; rec.z = fy; rec.w = m;
            *(float4*)&tm[p * 4] = rec;
        }
    }
}

// ---- kD: gather sampling, 16 px/block, 8 ch/thread (v8h) -> core16 ---------
__global__ __launch_bounds__(256) void kD_gather(const _Float16* __restrict__ xpad16,
                                                 const float* __restrict__ tapmeta,
                                                 _Float16* __restrict__ core16) {
    __shared__ float meta[16 * 36 * 4];             // 576 float4 = 9216 B
    int t = threadIdx.x;
    int eff = xcd_swizzle(blockIdx.x, 256);         // 2048 blocks -> batch-per-XCD
    int pix0 = eff * 16;
    const float4* src = (const float4*)(tapmeta + (size_t)pix0 * 36 * 4);
    for (int i = t; i < 576; i += 256) ((float4*)meta)[i] = src[i];
    __syncthreads();
    int px_l = t >> 4, s = t & 15;                  // px 0..15, slot 0..15
    int ch = s * 8, g = s >> 2;                     // 8 ch/thread, group = s/4
    int pix = pix0 + px_l;
    int b = pix >> 12;
    const _Float16* base = xpad16 + (size_t)b * GP2 * GP2 * CH + ch;
    const float* tmb = &meta[(size_t)(px_l * 36 + g * 9) * 4];
    float acc[8];
    #pragma unroll
    for (int j = 0; j < 8; j++) acc[j] = 0.f;
    #pragma unroll
    for (int p = 0; p < 9; p++) {
        float4 rec = *(const float4*)&tmb[p * 4];
        int off = __float_as_int(rec.x);
        float fx = rec.y, fy = rec.z, m = rec.w;
        float w11 = fx * fy;
        float w10 = fx - w11;
        float w01 = fy - w11;
        float w00 = 1.f - fx - fy + w11;
        w00 *= m; w10 *= m; w01 *= m; w11 *= m;
        v8h h0 = *(const v8h*)&base[off];
        v8h h1 = *(const v8h*)&base[off + CH];
        v8h h2 = *(const v8h*)&base[off + GP2 * CH];
        v8h h3 = *(const v8h*)&base[off + GP2 * CH + CH];
        #pragma unroll
        for (int j = 0; j < 8; j++)
            acc[j] += w00*(float)h0[j] + w10*(float)h1[j] + w01*(float)h2[j] + w11*(float)h3[j];
    }
    v8h res;
    #pragma unroll
    for (int j = 0; j < 8; j++) res[j] = (_Float16)acc[j];
    *(v8h*)&core16[(size_t)pix * CH + ch] = res;
}

// ---- g4: out_proj via MFMA + NHWC->NCHW store ------------------------------
__global__ __launch_bounds__(512) void g4_outproj(const _Float16* __restrict__ core16,
                                                  const _Float16* __restrict__ wp,
                                                  const float* __restrict__ bias,
                                                  float* __restrict__ out) {
    __shared__ _Float16 a16[64 * ASTRIDE];
    __shared__ float res[128 * 68];                 // [c][w], stride 68
    int t = threadIdx.x;
    int eff = xcd_swizzle(blockIdx.x, 64);          // 512 blocks -> batch-per-XCD
    int pix0 = eff * 64;
    const _Float16* src = core16 + (size_t)pix0 * CH;
    for (int q = t; q < 1024; q += 512)
        *(v8h*)&a16[(q >> 4) * ASTRIDE + (q & 15) * 8] = *(const v8h*)&src[q * 8];
    __syncthreads();
    int lane = t & 63, ncol = lane & 15;
    int ntb = ((t >> 6) & 1) * 4;
    v4f acc[4];
    #pragma unroll
    for (int j = 0; j < 4; j++) {
        float bv = bias[(ntb + j) * 16 + ncol];
        acc[j] = (v4f){bv, bv, bv, bv};
    }
    mfma_loop8(a16, wp, acc, t);
    int m0 = ((t >> 6) >> 1) * 16 + ((lane >> 4) * 4);
    #pragma unroll
    for (int j = 0; j < 4; j++)
        #pragma unroll
        for (int r = 0; r < 4; r++)
            res[((ntb + j) * 16 + ncol) * 68 + (m0 + r)] = acc[j][r];  // [c][w]
    __syncthreads();
    int b = pix0 >> 12, h = (pix0 >> 6) & 63;
    for (int q = t; q < 2048; q += 512) {
        int cc = q >> 4, w4 = (q & 15) * 4;
        float4 o = *(const float4*)&res[cc * 68 + w4];   // vector LDS read
        *(float4*)&out[(size_t)((b * CH + cc) * HH + h) * WWID + w4] = o;
    }
}

extern "C" void kernel_launch(void* const* d_in, const int* in_sizes, int n_in,
                              void* d_out, int out_size, void* d_ws, size_t ws_size,
                              hipStream_t stream) {
    const float* x        = (const float*)d_in[0];
    const float* conv_w   = (const float*)d_in[1];
    const float* conv_b   = (const float*)d_in[2];
    const float* in_proj_w= (const float*)d_in[3];
    const float* in_proj_b= (const float*)d_in[4];
    const float* dw_w     = (const float*)d_in[5];
    const float* dw_b     = (const float*)d_in[6];
    const float* ln_g     = (const float*)d_in[7];
    const float* ln_b     = (const float*)d_in[8];
    const float* off_w    = (const float*)d_in[9];
    const float* off_b    = (const float*)d_in[10];
    const float* mask_w   = (const float*)d_in[11];
    const float* mask_b   = (const float*)d_in[12];
    const float* out_proj_w = (const float*)d_in[13];
    const float* out_proj_b = (const float*)d_in[14];
    float* out = (float*)d_out;

    float* ws = (float*)d_ws;
    // float-offsets: wp | dwT | y16 | xpad16(70x70 guard) | core16 | tapmeta
    const size_t O_WP   = 0;
    const size_t O_DWT  = 32768;
    const size_t O_Y16  = 34816;                    // 2,097,152 floats (halfs)
    const size_t O_XP16 = O_Y16 + 2097152;          // 2,508,800 floats
    const size_t O_C16  = O_XP16 + 2508800;         // 2,097,152 floats
    const size_t O_TM   = O_C16 + 2097152;          // 4,718,592 floats
    _Float16* wp     = (_Float16*)(ws + O_WP);
    float*    dwT    = ws + O_DWT;
    _Float16* y16    = (_Float16*)(ws + O_Y16);
    _Float16* xpad16 = (_Float16*)(ws + O_XP16);
    _Float16* core16 = (_Float16*)(ws + O_C16);
    float*    tapmeta= ws + O_TM;

    _Float16* wp_conv = wp;
    _Float16* wp_in   = wp + (size_t)2048 * 8;
    _Float16* wp_om   = wp + (size_t)4096 * 8;
    _Float16* wp_out  = wp + (size_t)5888 * 8;

    p0_pack<<<64, 256, 0, stream>>>(conv_w, in_proj_w, off_w, mask_w, out_proj_w, dw_w, wp, dwT, xpad16);
    gA_conv_inproj<<<NPIX / 32, 256, 0, stream>>>(x, wp_conv, wp_in, conv_b, in_proj_b, y16, xpad16);
    gF_dwln_offmask<<<NPIX / 64, 512, 0, stream>>>(y16, wp_om, dwT, dw_b, ln_g, ln_b, off_b, mask_b, tapmeta);
    kD_gather<<<NPIX / 16, 256, 0, stream>>>(xpad16, tapmeta, core16);
    g4_outproj<<<NPIX / 64, 512, 0, stream>>>(core16, wp_out, out_proj_b, out);
}